// Round 2
// baseline (1219.939 us; speedup 1.0000x reference)
//
#include <hip/hip_runtime.h>
#include <math.h>

// ---------------------------------------------------------------------------
// EMD layer (Sinkhorn-OT logits) for MI355X.
// support: [32,512,8,8] f32, query: [256,512,8,8] f32 -> logits [256,32] f32.
//
// R2: sim phase moved to fp16 MFMA (mfma_f32_16x16x32_f16, fp32 accum).
//   K1 pool:   Bp[32,512], Qp[256,512]
//   K2 norm:   Uht[256,64,512] fp16 node-major, Vht[32,64,512] fp16 node-major
//   K3a/b:     a/b marginals (fp32, unchanged from R1)
//   K4 emd:    MFMA sim tile -> M = exp((sim-1)/eps) -> LDS transpose to
//              (ig,jg) 8x8 layout -> 100 exp-domain Sinkhorn iters -> logits
// ---------------------------------------------------------------------------

#define DEV static __device__ __forceinline__

typedef _Float16 half8 __attribute__((ext_vector_type(8)));
typedef float floatx4 __attribute__((ext_vector_type(4)));

DEV float fast_rcp(float x) {
#if __has_builtin(__builtin_amdgcn_rcpf)
    return __builtin_amdgcn_rcpf(x);
#else
    return 1.0f / x;
#endif
}
DEV float fexp2(float x) {
#if __has_builtin(__builtin_amdgcn_exp2f)
    return __builtin_amdgcn_exp2f(x);
#else
    return exp2f(x);
#endif
}
DEV float flog2(float x) {
#if __has_builtin(__builtin_amdgcn_logf)
    return __builtin_amdgcn_logf(x);
#else
    return log2f(x);
#endif
}

#define K_SIM2M 28.853900817779268f    // 20/ln2 : M = 2^((sim-1)*K_SIM2M)
#define K_M2SIM 0.034657359027997264f  // 0.05*ln2 : sim = 1 + log2(M)*K_M2SIM

// ---------------- K1: pooled means over the 64 spatial nodes ----------------
__global__ void pool_kernel(const float* __restrict__ support,
                            const float* __restrict__ query,
                            float* __restrict__ Bp, float* __restrict__ Qp) {
    int idx = blockIdx.x * 256 + threadIdx.x;
    if (idx >= 288 * 512) return;
    const float* src;
    float* dst;
    if (idx < 32 * 512) { src = support + (size_t)idx * 64; dst = Bp + idx; }
    else { int k = idx - 32 * 512; src = query + (size_t)k * 64; dst = Qp + k; }
    float s = 0.f;
#pragma unroll
    for (int i = 0; i < 16; ++i) {
        float4 v = ((const float4*)src)[i];
        s += v.x + v.y + v.z + v.w;
    }
    *dst = s * (1.0f / 64.0f);
}

// ------ K2: center over C, L2-normalize over C, emit fp16 node-major --------
// Uht[q][node][c], Vht[w][node][c]  (so MFMA A/B frags are 16B contiguous)
__global__ void norm_kernel(const float* __restrict__ support,
                            const float* __restrict__ query,
                            _Float16* __restrict__ Vht, _Float16* __restrict__ Uht) {
    int gid  = blockIdx.x * 256 + threadIdx.x;
    int wid  = gid >> 6;       // sample 0..287
    int lane = gid & 63;       // node
    if (wid >= 288) return;
    const float* src;
    _Float16* dst;
    if (wid < 32) { src = support + (size_t)wid * 32768; dst = Vht + (size_t)wid * 32768; }
    else { src = query + (size_t)(wid - 32) * 32768; dst = Uht + (size_t)(wid - 32) * 32768; }
    float s1 = 0.f, s2 = 0.f;
#pragma unroll 8
    for (int c = 0; c < 512; ++c) {
        float x = src[c * 64 + lane];
        s1 += x;
        s2 += x * x;
    }
    float mu  = s1 * (1.0f / 512.0f);
    float ss  = s2 - 512.0f * mu * mu;
    float inv = 1.0f / fmaxf(sqrtf(fmaxf(ss, 0.0f)), 1e-8f);
    _Float16* drow = dst + (size_t)lane * 512;
#pragma unroll 4
    for (int c0 = 0; c0 < 512; c0 += 8) {
        half8 buf;
#pragma unroll
        for (int j = 0; j < 8; ++j)
            buf[j] = (_Float16)((src[(c0 + j) * 64 + lane] - mu) * inv);
        *(half8*)(drow + c0) = buf;
    }
}

// --------- K3a: a-marginals (unchanged from R1, fp32 exact) -----------------
__global__ void __launch_bounds__(256)
amarg_kernel(const float* __restrict__ query, const float* __restrict__ Bp,
             float* __restrict__ a_out) {
    __shared__ float BpL[32 * 64];
    int q    = blockIdx.x;
    int lane = threadIdx.x & 63;
    int wq   = threadIdx.x >> 6;
    float acc[8] = {0, 0, 0, 0, 0, 0, 0, 0};
    for (int cc = 0; cc < 512; cc += 64) {
        __syncthreads();
        for (int t = threadIdx.x; t < 2048; t += 256) {
            int w = t >> 6, c = t & 63;
            BpL[t] = Bp[w * 512 + cc + c];
        }
        __syncthreads();
        for (int c = 0; c < 64; ++c) {
            float qv = query[((size_t)q * 512 + cc + c) * 64 + lane];
#pragma unroll
            for (int k = 0; k < 8; ++k)
                acc[k] += qv * BpL[(wq * 8 + k) * 64 + c];
        }
    }
#pragma unroll
    for (int k = 0; k < 8; ++k) {
        float v = fmaxf(acc[k], 0.0f) + 0.001f;
        v += 1e-5f;
        float s = v;
        s += __shfl_xor(s, 1);  s += __shfl_xor(s, 2);  s += __shfl_xor(s, 4);
        s += __shfl_xor(s, 8);  s += __shfl_xor(s, 16); s += __shfl_xor(s, 32);
        int w = wq * 8 + k;
        a_out[((size_t)q * 32 + w) * 64 + lane] = v * (64.0f / s);
    }
}

// --------- K3b: b-marginals (unchanged from R1) -----------------------------
__global__ void __launch_bounds__(256)
bmarg_kernel(const float* __restrict__ support, const float* __restrict__ Qp,
             float* __restrict__ b_out) {
    __shared__ float QpL[32 * 64];
    int w    = blockIdx.x >> 3;
    int qg   = blockIdx.x & 7;
    int lane = threadIdx.x & 63;
    int qq   = threadIdx.x >> 6;
    float acc[8] = {0, 0, 0, 0, 0, 0, 0, 0};
    for (int cc = 0; cc < 512; cc += 64) {
        __syncthreads();
        for (int t = threadIdx.x; t < 2048; t += 256) {
            int ql = t >> 6, c = t & 63;
            QpL[t] = Qp[(size_t)(qg * 32 + ql) * 512 + cc + c];
        }
        __syncthreads();
        for (int c = 0; c < 64; ++c) {
            float sv = support[((size_t)w * 512 + cc + c) * 64 + lane];
#pragma unroll
            for (int k = 0; k < 8; ++k)
                acc[k] += sv * QpL[(qq * 8 + k) * 64 + c];
        }
    }
#pragma unroll
    for (int k = 0; k < 8; ++k) {
        float v = fmaxf(acc[k], 0.0f) + 0.001f;
        v += 1e-5f;
        float s = v;
        s += __shfl_xor(s, 1);  s += __shfl_xor(s, 2);  s += __shfl_xor(s, 4);
        s += __shfl_xor(s, 8);  s += __shfl_xor(s, 16); s += __shfl_xor(s, 32);
        int q = qg * 32 + qq * 8 + k;
        b_out[((size_t)w * 256 + q) * 64 + lane] = v * (64.0f / s);
    }
}

// --------- K4: MFMA sim + LDS transpose + Sinkhorn(100) + logits ------------
// Wave per (q,w). MFMA C-layout: C[row=(l>>4)*4+reg+16*tm][col=(l&15)+16*tn].
// Sinkhorn layout (R1-verified): lane=(ig,jg) owns rows 8ig..+7, cols 8jg..+7.
__global__ void __launch_bounds__(256)
emd_kernel(const _Float16* __restrict__ Uht, const _Float16* __restrict__ Vht,
           const float* __restrict__ a_arr, const float* __restrict__ b_arr,
           float* __restrict__ out) {
    __shared__ __align__(16) float T[2][64 * 64];   // 32 KB

    int bid  = blockIdx.x;          // 2048
    int w    = bid & 31;
    int qg   = bid >> 5;
    int wave = threadIdx.x >> 6;    // 0..3
    int lane = threadIdx.x & 63;
    int q    = qg * 4 + wave;
    int lo16 = lane & 15;
    int hi4  = lane >> 4;
    int ig   = lane >> 3;           // Sinkhorn row group
    int jg   = lane & 7;            // Sinkhorn col group

    // ---- phase 1: sim tile via fp16 MFMA (A=Uht[q] 64x512, B=Vht[w]^T) ----
    floatx4 acc[4][4];
#pragma unroll
    for (int tm = 0; tm < 4; ++tm)
#pragma unroll
        for (int tn = 0; tn < 4; ++tn)
            acc[tm][tn] = (floatx4){0.f, 0.f, 0.f, 0.f};

    const _Float16* Abase = Uht + (size_t)q * 32768;
    const _Float16* Bbase = Vht + (size_t)w * 32768;
#pragma unroll 1
    for (int kk = 0; kk < 16; ++kk) {
        int kc = kk * 32 + hi4 * 8;
        half8 af[4], bf[4];
#pragma unroll
        for (int t = 0; t < 4; ++t) {
            af[t] = *(const half8*)(Abase + (size_t)(t * 16 + lo16) * 512 + kc);
            bf[t] = *(const half8*)(Bbase + (size_t)(t * 16 + lo16) * 512 + kc);
        }
#pragma unroll
        for (int tm = 0; tm < 4; ++tm)
#pragma unroll
            for (int tn = 0; tn < 4; ++tn)
                acc[tm][tn] = __builtin_amdgcn_mfma_f32_16x16x32_f16(
                    af[tm], bf[tn], acc[tm][tn], 0, 0, 0);
    }

    // ---- phase 2: M = exp((sim-1)/eps), transpose C-layout -> (ig,jg) -----
    float M[8][8];
#pragma unroll 1
    for (int round = 0; round < 2; ++round) {
        if ((wave >> 1) == round) {
            float* buf = T[wave & 1];
#pragma unroll
            for (int tm = 0; tm < 4; ++tm)
#pragma unroll
                for (int tn = 0; tn < 4; ++tn)
#pragma unroll
                    for (int r = 0; r < 4; ++r)
                        buf[(tm * 16 + hi4 * 4 + r) * 64 + tn * 16 + lo16] =
                            fexp2((acc[tm][tn][r] - 1.0f) * K_SIM2M);
        }
        __syncthreads();
        if ((wave >> 1) == round) {
            const float* buf = T[wave & 1];
#pragma unroll
            for (int r = 0; r < 8; ++r) {
                float4 m0 = *(const float4*)(buf + (ig * 8 + r) * 64 + jg * 8);
                float4 m1 = *(const float4*)(buf + (ig * 8 + r) * 64 + jg * 8 + 4);
                M[r][0] = m0.x; M[r][1] = m0.y; M[r][2] = m0.z; M[r][3] = m0.w;
                M[r][4] = m1.x; M[r][5] = m1.y; M[r][6] = m1.z; M[r][7] = m1.w;
            }
        }
        __syncthreads();
    }

    // ---- marginals for this lane's rows/cols (R1 layout) ----
    const float* ap = a_arr + ((size_t)q * 32 + w) * 64 + ig * 8;
    float4 a0 = *(const float4*)ap, a1 = *(const float4*)(ap + 4);
    float az[8] = {a0.x, a0.y, a0.z, a0.w, a1.x, a1.y, a1.z, a1.w};
    const float* bp = b_arr + ((size_t)w * 256 + q) * 64 + jg * 8;
    float4 b0 = *(const float4*)bp, b1 = *(const float4*)(bp + 4);
    float bz[8] = {b0.x, b0.y, b0.z, b0.w, b1.x, b1.y, b1.z, b1.w};

    // ---- phase 3: 100 Sinkhorn iterations, exp-domain (R1-verified) ----
    float wv[8], zv[8];
#pragma unroll
    for (int c = 0; c < 8; ++c) wv[c] = 1.0f;

#pragma unroll 1
    for (int it = 0; it < 100; ++it) {
        float y[8];
#pragma unroll
        for (int r = 0; r < 8; ++r) {
            float s = 0.f;
#pragma unroll
            for (int c = 0; c < 8; ++c) s += M[r][c] * wv[c];
            y[r] = s;
        }
#pragma unroll
        for (int r = 0; r < 8; ++r) {
            y[r] += __shfl_xor(y[r], 1);
            y[r] += __shfl_xor(y[r], 2);
            y[r] += __shfl_xor(y[r], 4);
            zv[r] = az[r] * fast_rcp(y[r]);
        }
        float t8[8];
#pragma unroll
        for (int c = 0; c < 8; ++c) t8[c] = 0.f;
#pragma unroll
        for (int r = 0; r < 8; ++r)
#pragma unroll
            for (int c = 0; c < 8; ++c) t8[c] += M[r][c] * zv[r];
#pragma unroll
        for (int c = 0; c < 8; ++c) {
            t8[c] += __shfl_xor(t8[c], 8);
            t8[c] += __shfl_xor(t8[c], 16);
            t8[c] += __shfl_xor(t8[c], 32);
            wv[c] = bz[c] * fast_rcp(t8[c]);
        }
    }

    // ---- phase 4: logits = sum(sim * flow) * T/N ; sim = 1 + ln(M)*eps ----
    float s = 0.f;
#pragma unroll
    for (int r = 0; r < 8; ++r)
#pragma unroll
        for (int c = 0; c < 8; ++c) {
            float sim  = fmaf(flog2(M[r][c]), K_M2SIM, 1.0f);
            float flow = zv[r] * M[r][c] * wv[c];
            s = fmaf(sim, flow, s);
        }
    s += __shfl_xor(s, 1);  s += __shfl_xor(s, 2);  s += __shfl_xor(s, 4);
    s += __shfl_xor(s, 8);  s += __shfl_xor(s, 16); s += __shfl_xor(s, 32);
    if (lane == 0) out[q * 32 + w] = s * 0.1953125f;   // 12.5/64
}

// ---------------------------------------------------------------------------
extern "C" void kernel_launch(void* const* d_in, const int* in_sizes, int n_in,
                              void* d_out, int out_size, void* d_ws, size_t ws_size,
                              hipStream_t stream) {
    (void)in_sizes; (void)n_in; (void)out_size; (void)ws_size;
    const float* support = (const float*)d_in[0];   // 32*512*64
    const float* query   = (const float*)d_in[1];   // 256*512*64

    _Float16* Uht = (_Float16*)d_ws;                // 8,388,608 halves (16 MB)
    _Float16* Vht = Uht + 8388608;                  // 1,048,576 halves (2 MB)
    float* Bp = (float*)(Vht + 1048576);            //    16,384 f
    float* Qp = Bp + 16384;                         //   131,072 f
    float* aA = Qp + 131072;                        //   524,288 f
    float* bA = aA + 524288;                        //   524,288 f

    pool_kernel <<<576, 256, 0, stream>>>(support, query, Bp, Qp);
    norm_kernel <<<72, 256, 0, stream>>>(support, query, Vht, Uht);
    amarg_kernel<<<256, 256, 0, stream>>>(query, Bp, aA);
    bmarg_kernel<<<256, 256, 0, stream>>>(support, Qp, bA);
    emd_kernel  <<<2048, 256, 0, stream>>>(Uht, Vht, aA, bA, (float*)d_out);
}

// Round 3
// 501.261 us; speedup vs baseline: 2.4337x; 2.4337x over previous
//
#include <hip/hip_runtime.h>
#include <math.h>

// ---------------------------------------------------------------------------
// EMD layer (Sinkhorn-OT logits) for MI355X.
// support: [32,512,8,8] f32, query: [256,512,8,8] f32 -> logits [256,32] f32.
//
// R3: Sinkhorn restructured as reduce-scatter + all-gather on a lane-xor
//     permuted register layout (7 shfl per reduce instead of 24, 2 rcp/iter
//     instead of 16), bit-exact early exit, VGPR capped at 128 (4 waves/SIMD),
//     norm_kernel rewritten with LDS transpose for coalesced fp16 stores.
// ---------------------------------------------------------------------------

#define DEV static __device__ __forceinline__

typedef _Float16 half8 __attribute__((ext_vector_type(8)));
typedef float floatx4 __attribute__((ext_vector_type(4)));

DEV float fast_rcp(float x) {
#if __has_builtin(__builtin_amdgcn_rcpf)
    return __builtin_amdgcn_rcpf(x);
#else
    return 1.0f / x;
#endif
}
DEV float fexp2(float x) {
#if __has_builtin(__builtin_amdgcn_exp2f)
    return __builtin_amdgcn_exp2f(x);
#else
    return exp2f(x);
#endif
}
DEV float flog2(float x) {
#if __has_builtin(__builtin_amdgcn_logf)
    return __builtin_amdgcn_logf(x);
#else
    return log2f(x);
#endif
}

#define K_SIM2M 28.853900817779268f    // 20/ln2 : M = 2^((sim-1)*K_SIM2M)
#define K_M2SIM 0.034657359027997264f  // 0.05*ln2 : sim = 1 + log2(M)*K_M2SIM

// ---------------- K1: pooled means over the 64 spatial nodes ----------------
__global__ void pool_kernel(const float* __restrict__ support,
                            const float* __restrict__ query,
                            float* __restrict__ Bp, float* __restrict__ Qp) {
    int idx = blockIdx.x * 256 + threadIdx.x;
    if (idx >= 288 * 512) return;
    const float* src;
    float* dst;
    if (idx < 32 * 512) { src = support + (size_t)idx * 64; dst = Bp + idx; }
    else { int k = idx - 32 * 512; src = query + (size_t)k * 64; dst = Qp + k; }
    float s = 0.f;
#pragma unroll
    for (int i = 0; i < 16; ++i) {
        float4 v = ((const float4*)src)[i];
        s += v.x + v.y + v.z + v.w;
    }
    *dst = s * (1.0f / 64.0f);
}

// ------ K2: center over C, L2-normalize over C, emit fp16 node-major --------
// Block per sample. LDS transpose so fp16 stores are coalesced half8.
__global__ void __launch_bounds__(256)
norm_kernel(const float* __restrict__ support, const float* __restrict__ query,
            _Float16* __restrict__ Vht, _Float16* __restrict__ Uht) {
    __shared__ float red1[4][64];
    __shared__ float red2[4][64];
    __shared__ float muL[64], invL[64];
    __shared__ float tile[128][65];   // +1 pad: 4-way max on transposed reads

    int sid = blockIdx.x;             // 0..287
    const float* src;
    _Float16* dst;
    if (sid < 32) { src = support + (size_t)sid * 32768; dst = Vht + (size_t)sid * 32768; }
    else { src = query + (size_t)(sid - 32) * 32768; dst = Uht + (size_t)(sid - 32) * 32768; }

    int node = threadIdx.x & 63;
    int cq   = threadIdx.x >> 6;      // c-quarter 0..3

    float s1 = 0.f, s2 = 0.f;
#pragma unroll 4
    for (int j = 0; j < 128; ++j) {
        float x = src[(cq * 128 + j) * 64 + node];
        s1 += x; s2 += x * x;
    }
    red1[cq][node] = s1;
    red2[cq][node] = s2;
    __syncthreads();
    if (threadIdx.x < 64) {
        float t1 = red1[0][node] + red1[1][node] + red1[2][node] + red1[3][node];
        float t2 = red2[0][node] + red2[1][node] + red2[2][node] + red2[3][node];
        float mu = t1 * (1.0f / 512.0f);
        float ss = t2 - 512.0f * mu * mu;
        muL[node]  = mu;
        invL[node] = 1.0f / fmaxf(sqrtf(fmaxf(ss, 0.0f)), 1e-8f);
    }
    __syncthreads();

    for (int ch = 0; ch < 4; ++ch) {          // 4 chunks of 128 c's
        float mu = muL[node], inv = invL[node];
#pragma unroll 4
        for (int j = 0; j < 32; ++j) {
            int cl = cq * 32 + j;
            float x = src[(ch * 128 + cl) * 64 + node];
            tile[cl][node] = (x - mu) * inv;
        }
        __syncthreads();
#pragma unroll
        for (int r = 0; r < 4; ++r) {
            int lin = r * 256 + threadIdx.x;
            int nd  = lin >> 4;               // 16 half8 per node-row of 128 c
            int c8  = lin & 15;
            half8 v;
#pragma unroll
            for (int i = 0; i < 8; ++i) v[i] = (_Float16)tile[c8 * 8 + i][nd];
            *(half8*)(dst + (size_t)nd * 512 + ch * 128 + c8 * 8) = v;
        }
        __syncthreads();
    }
}

// --------- K3a: a-marginals (unchanged) -------------------------------------
__global__ void __launch_bounds__(256)
amarg_kernel(const float* __restrict__ query, const float* __restrict__ Bp,
             float* __restrict__ a_out) {
    __shared__ float BpL[32 * 64];
    int q    = blockIdx.x;
    int lane = threadIdx.x & 63;
    int wq   = threadIdx.x >> 6;
    float acc[8] = {0, 0, 0, 0, 0, 0, 0, 0};
    for (int cc = 0; cc < 512; cc += 64) {
        __syncthreads();
        for (int t = threadIdx.x; t < 2048; t += 256) {
            int w = t >> 6, c = t & 63;
            BpL[t] = Bp[w * 512 + cc + c];
        }
        __syncthreads();
        for (int c = 0; c < 64; ++c) {
            float qv = query[((size_t)q * 512 + cc + c) * 64 + lane];
#pragma unroll
            for (int k = 0; k < 8; ++k)
                acc[k] += qv * BpL[(wq * 8 + k) * 64 + c];
        }
    }
#pragma unroll
    for (int k = 0; k < 8; ++k) {
        float v = fmaxf(acc[k], 0.0f) + 0.001f;
        v += 1e-5f;
        float s = v;
        s += __shfl_xor(s, 1);  s += __shfl_xor(s, 2);  s += __shfl_xor(s, 4);
        s += __shfl_xor(s, 8);  s += __shfl_xor(s, 16); s += __shfl_xor(s, 32);
        int w = wq * 8 + k;
        a_out[((size_t)q * 32 + w) * 64 + lane] = v * (64.0f / s);
    }
}

// --------- K3b: b-marginals (unchanged) -------------------------------------
__global__ void __launch_bounds__(256)
bmarg_kernel(const float* __restrict__ support, const float* __restrict__ Qp,
             float* __restrict__ b_out) {
    __shared__ float QpL[32 * 64];
    int w    = blockIdx.x >> 3;
    int qg   = blockIdx.x & 7;
    int lane = threadIdx.x & 63;
    int qq   = threadIdx.x >> 6;
    float acc[8] = {0, 0, 0, 0, 0, 0, 0, 0};
    for (int cc = 0; cc < 512; cc += 64) {
        __syncthreads();
        for (int t = threadIdx.x; t < 2048; t += 256) {
            int ql = t >> 6, c = t & 63;
            QpL[t] = Qp[(size_t)(qg * 32 + ql) * 512 + cc + c];
        }
        __syncthreads();
        for (int c = 0; c < 64; ++c) {
            float sv = support[((size_t)w * 512 + cc + c) * 64 + lane];
#pragma unroll
            for (int k = 0; k < 8; ++k)
                acc[k] += sv * QpL[(qq * 8 + k) * 64 + c];
        }
    }
#pragma unroll
    for (int k = 0; k < 8; ++k) {
        float v = fmaxf(acc[k], 0.0f) + 0.001f;
        v += 1e-5f;
        float s = v;
        s += __shfl_xor(s, 1);  s += __shfl_xor(s, 2);  s += __shfl_xor(s, 4);
        s += __shfl_xor(s, 8);  s += __shfl_xor(s, 16); s += __shfl_xor(s, 32);
        int q = qg * 32 + qq * 8 + k;
        b_out[((size_t)w * 256 + q) * 64 + lane] = v * (64.0f / s);
    }
}

// --------- K4: MFMA sim + permuted transpose + Sinkhorn + logits ------------
// Wave per (q,w). lane=(ig,jg). Permuted register layout:
//   Mpp[t][s] = M[ig*8 + (jg^t)][jg*8 + (ig^s)]
// so reduce-scatter (7 shfl) and all-gather (7 shfl) use compile-time slots.
// Lane owns row ig*8+jg (slot t=0) and col jg*8+ig (slot s=0).
__global__ void __launch_bounds__(256, 4)
emd_kernel(const _Float16* __restrict__ Uht, const _Float16* __restrict__ Vht,
           const float* __restrict__ a_arr, const float* __restrict__ b_arr,
           float* __restrict__ out) {
    __shared__ __align__(16) float T[2][64 * 64];   // 32 KB

    int bid  = blockIdx.x;          // 2048
    int w    = bid & 31;
    int qg   = bid >> 5;
    int wave = threadIdx.x >> 6;    // 0..3
    int lane = threadIdx.x & 63;
    int q    = qg * 4 + wave;
    int lo16 = lane & 15;
    int hi4  = lane >> 4;
    int ig   = lane >> 3;
    int jg   = lane & 7;

    // ---- phase 1: sim tile via fp16 MFMA ----
    floatx4 acc[4][4];
#pragma unroll
    for (int tm = 0; tm < 4; ++tm)
#pragma unroll
        for (int tn = 0; tn < 4; ++tn)
            acc[tm][tn] = (floatx4){0.f, 0.f, 0.f, 0.f};

    const _Float16* Abase = Uht + (size_t)q * 32768;
    const _Float16* Bbase = Vht + (size_t)w * 32768;
#pragma unroll 1
    for (int kk = 0; kk < 16; ++kk) {
        int kc = kk * 32 + hi4 * 8;
        half8 bf[4];
#pragma unroll
        for (int t = 0; t < 4; ++t)
            bf[t] = *(const half8*)(Bbase + (size_t)(t * 16 + lo16) * 512 + kc);
#pragma unroll
        for (int tm = 0; tm < 4; ++tm) {
            half8 af = *(const half8*)(Abase + (size_t)(tm * 16 + lo16) * 512 + kc);
#pragma unroll
            for (int tn = 0; tn < 4; ++tn)
                acc[tm][tn] = __builtin_amdgcn_mfma_f32_16x16x32_f16(
                    af, bf[tn], acc[tm][tn], 0, 0, 0);
        }
    }

    // ---- phase 2: exp + LDS roundtrip into permuted layout ----
    // Writer stores M[row][col] at T2[row][col>>3][(col&7) ^ (row>>3)].
    // Reader (ig,jg) slot (t,s) reads T2[ig*8+(jg^t)][jg][s]
    //   = M[ig*8+(jg^t)][jg*8 + ((ig*8+(jg^t))>>3 ^ s)] = M[row][jg*8+(ig^s)]. OK
    float Mpp[8][8];
#pragma unroll 1
    for (int round = 0; round < 2; ++round) {
        if ((wave >> 1) == round) {
            float* buf = T[wave & 1];
#pragma unroll
            for (int tm = 0; tm < 4; ++tm)
#pragma unroll
                for (int tn = 0; tn < 4; ++tn)
#pragma unroll
                    for (int r = 0; r < 4; ++r) {
                        int row = tm * 16 + hi4 * 4 + r;
                        int col = tn * 16 + lo16;
                        int sp  = (col & 7) ^ (row >> 3);
                        buf[row * 64 + (col & ~7) + sp] =
                            fexp2((acc[tm][tn][r] - 1.0f) * K_SIM2M);
                    }
        }
        __syncthreads();
        if ((wave >> 1) == round) {
            const float* buf = T[wave & 1];
#pragma unroll
            for (int t = 0; t < 8; ++t) {
                const float* p = buf + (ig * 8 + (jg ^ t)) * 64 + jg * 8;
                float4 m0 = *(const float4*)p;
                float4 m1 = *(const float4*)(p + 4);
                Mpp[t][0] = m0.x; Mpp[t][1] = m0.y; Mpp[t][2] = m0.z; Mpp[t][3] = m0.w;
                Mpp[t][4] = m1.x; Mpp[t][5] = m1.y; Mpp[t][6] = m1.z; Mpp[t][7] = m1.w;
            }
        }
        __syncthreads();
    }

    float a_own = a_arr[((size_t)q * 32 + w) * 64 + ig * 8 + jg];   // row ig*8+jg
    float b_own = b_arr[((size_t)w * 256 + q) * 64 + jg * 8 + ig];  // col jg*8+ig

    // ---- phase 3: Sinkhorn, reduce-scatter + all-gather, early exit ----
    float wvp[8];   // wvp[s] = w[jg*8 + (ig^s)]
#pragma unroll
    for (int s = 0; s < 8; ++s) wvp[s] = 1.0f;
    float q8[8];    // q8[t] = z[ig*8 + (jg^t)]
    float z_prev = -1.f, w_prev = -1.f;

#pragma unroll 1
    for (int it = 0; it < 100; ++it) {
        // row matvec partials (rows jg^t, cols jg*8..+7 in s-permuted order)
        float p[8];
#pragma unroll
        for (int t = 0; t < 8; ++t) {
            float s = Mpp[t][0] * wvp[0];
#pragma unroll
            for (int c = 1; c < 8; ++c) s = fmaf(Mpp[t][c], wvp[c], s);
            p[t] = s;
        }
        // reduce-scatter over jg: lane-xor {4,2,1} <-> slot-xor {4,2,1}
        p[0] += __shfl_xor(p[4], 4); p[1] += __shfl_xor(p[5], 4);
        p[2] += __shfl_xor(p[6], 4); p[3] += __shfl_xor(p[7], 4);
        p[0] += __shfl_xor(p[2], 2); p[1] += __shfl_xor(p[3], 2);
        p[0] += __shfl_xor(p[1], 1);
        float z_own = a_own * fast_rcp(p[0]);
        // all-gather z over jg octet
        q8[0] = z_own;
        q8[1] = __shfl_xor(q8[0], 1);
        q8[2] = __shfl_xor(q8[0], 2); q8[3] = __shfl_xor(q8[1], 2);
        q8[4] = __shfl_xor(q8[0], 4); q8[5] = __shfl_xor(q8[1], 4);
        q8[6] = __shfl_xor(q8[2], 4); q8[7] = __shfl_xor(q8[3], 4);
        // col matvec partials
        float cp[8];
#pragma unroll
        for (int s = 0; s < 8; ++s) {
            float v = Mpp[0][s] * q8[0];
#pragma unroll
            for (int t = 1; t < 8; ++t) v = fmaf(Mpp[t][s], q8[t], v);
            cp[s] = v;
        }
        // reduce-scatter over ig: lane-xor {32,16,8} <-> slot-xor {4,2,1}
        cp[0] += __shfl_xor(cp[4], 32); cp[1] += __shfl_xor(cp[5], 32);
        cp[2] += __shfl_xor(cp[6], 32); cp[3] += __shfl_xor(cp[7], 32);
        cp[0] += __shfl_xor(cp[2], 16); cp[1] += __shfl_xor(cp[3], 16);
        cp[0] += __shfl_xor(cp[1], 8);
        float w_own = b_own * fast_rcp(cp[0]);
        // all-gather w over ig octet
        wvp[0] = w_own;
        wvp[1] = __shfl_xor(wvp[0], 8);
        wvp[2] = __shfl_xor(wvp[0], 16); wvp[3] = __shfl_xor(wvp[1], 16);
        wvp[4] = __shfl_xor(wvp[0], 32); wvp[5] = __shfl_xor(wvp[1], 32);
        wvp[6] = __shfl_xor(wvp[2], 32); wvp[7] = __shfl_xor(wvp[3], 32);
        // bit-exact stationarity -> remaining iterations are exact no-ops
        bool same = (z_own == z_prev) && (w_own == w_prev);
        z_prev = z_own; w_prev = w_own;
        if (__all(same)) break;
    }

    // ---- phase 4: logits = sum(sim * flow) * T/N ; sim = 1 + ln(M)*eps ----
    float s = 0.f;
#pragma unroll
    for (int t = 0; t < 8; ++t)
#pragma unroll
        for (int c = 0; c < 8; ++c) {
            float m    = Mpp[t][c];
            float sim  = fmaf(flog2(m), K_M2SIM, 1.0f);
            float flow = q8[t] * m * wvp[c];
            s = fmaf(sim, flow, s);
        }
    s += __shfl_xor(s, 1);  s += __shfl_xor(s, 2);  s += __shfl_xor(s, 4);
    s += __shfl_xor(s, 8);  s += __shfl_xor(s, 16); s += __shfl_xor(s, 32);
    if (lane == 0) out[q * 32 + w] = s * 0.1953125f;   // 12.5/64
}

// ---------------------------------------------------------------------------
extern "C" void kernel_launch(void* const* d_in, const int* in_sizes, int n_in,
                              void* d_out, int out_size, void* d_ws, size_t ws_size,
                              hipStream_t stream) {
    (void)in_sizes; (void)n_in; (void)out_size; (void)ws_size;
    const float* support = (const float*)d_in[0];   // 32*512*64
    const float* query   = (const float*)d_in[1];   // 256*512*64

    _Float16* Uht = (_Float16*)d_ws;                // 16 MB
    _Float16* Vht = Uht + 8388608;                  //  2 MB
    float* Bp = (float*)(Vht + 1048576);
    float* Qp = Bp + 16384;
    float* aA = Qp + 131072;
    float* bA = aA + 524288;

    pool_kernel <<<576, 256, 0, stream>>>(support, query, Bp, Qp);
    norm_kernel <<<288, 256, 0, stream>>>(support, query, Vht, Uht);
    amarg_kernel<<<256, 256, 0, stream>>>(query, Bp, aA);
    bmarg_kernel<<<256, 256, 0, stream>>>(support, Qp, bA);
    emd_kernel  <<<2048, 256, 0, stream>>>(Uht, Vht, aA, bA, (float*)d_out);
}

// Round 4
// 286.912 us; speedup vs baseline: 4.2520x; 1.7471x over previous
//
#include <hip/hip_runtime.h>
#include <math.h>

// ---------------------------------------------------------------------------
// EMD layer (Sinkhorn-OT logits) for MI355X.
// support: [32,512,8,8] f32, query: [256,512,8,8] f32 -> logits [256,32] f32.
//
// R4: (1) Gibbs kernel held as per-tile-rescaled fp16 (32 VGPRs) -> no scratch
//     spill at launch_bounds(256,4); flow is invariant to global M scale, sim
//     recovered as smax + eps*ln(M').  (2) tolerance-based early exit (rel
//     1e-5) instead of bit-exact.  (3) pool fused into norm (transposed BpT/
//     QpT), amarg/bmarg read weights via broadcast ds_read_b128.
// ---------------------------------------------------------------------------

#define DEV static __device__ __forceinline__

typedef _Float16 half8 __attribute__((ext_vector_type(8)));
typedef float floatx4 __attribute__((ext_vector_type(4)));

DEV float fast_rcp(float x) {
#if __has_builtin(__builtin_amdgcn_rcpf)
    return __builtin_amdgcn_rcpf(x);
#else
    return 1.0f / x;
#endif
}
DEV float fexp2(float x) {
#if __has_builtin(__builtin_amdgcn_exp2f)
    return __builtin_amdgcn_exp2f(x);
#else
    return exp2f(x);
#endif
}
DEV float flog2(float x) {
#if __has_builtin(__builtin_amdgcn_logf)
    return __builtin_amdgcn_logf(x);
#else
    return log2f(x);
#endif
}

#define K_SIM2M 28.853900817779268f    // 20/ln2 : M = 2^((sim-1)*K_SIM2M)
#define K_M2SIM 0.034657359027997264f  // 0.05*ln2 : sim = 1 + log2(M)*K_M2SIM

// ------ K1: center+normalize over C -> fp16 node-major, + pooled means ------
// 288 blocks: sid<32 -> support (Vht, BpT[c][32]); else query (Uht, QpT[c][256]).
__global__ void __launch_bounds__(256)
norm_kernel(const float* __restrict__ support, const float* __restrict__ query,
            _Float16* __restrict__ Vht, _Float16* __restrict__ Uht,
            float* __restrict__ BpT, float* __restrict__ QpT) {
    __shared__ float red1[4][64];
    __shared__ float red2[4][64];
    __shared__ float muL[64], invL[64];
    __shared__ float tile[128][65];

    int sid = blockIdx.x;             // 0..287
    const float* src;
    _Float16* dst;
    float* poolT;
    int pstride, pidx;
    if (sid < 32) {
        src = support + (size_t)sid * 32768; dst = Vht + (size_t)sid * 32768;
        poolT = BpT; pstride = 32; pidx = sid;
    } else {
        src = query + (size_t)(sid - 32) * 32768; dst = Uht + (size_t)(sid - 32) * 32768;
        poolT = QpT; pstride = 256; pidx = sid - 32;
    }

    // pooled mean over the 64 nodes, transposed store poolT[c][sample]
    for (int c = threadIdx.x; c < 512; c += 256) {
        const float4* p4 = (const float4*)(src + (size_t)c * 64);
        float s = 0.f;
#pragma unroll
        for (int i = 0; i < 16; ++i) { float4 v = p4[i]; s += v.x + v.y + v.z + v.w; }
        poolT[(size_t)c * pstride + pidx] = s * (1.0f / 64.0f);
    }

    int node = threadIdx.x & 63;
    int cq   = threadIdx.x >> 6;

    float s1 = 0.f, s2 = 0.f;
#pragma unroll 4
    for (int j = 0; j < 128; ++j) {
        float x = src[(cq * 128 + j) * 64 + node];
        s1 += x; s2 += x * x;
    }
    red1[cq][node] = s1;
    red2[cq][node] = s2;
    __syncthreads();
    if (threadIdx.x < 64) {
        float t1 = red1[0][node] + red1[1][node] + red1[2][node] + red1[3][node];
        float t2 = red2[0][node] + red2[1][node] + red2[2][node] + red2[3][node];
        float mu = t1 * (1.0f / 512.0f);
        float ss = t2 - 512.0f * mu * mu;
        muL[node]  = mu;
        invL[node] = 1.0f / fmaxf(sqrtf(fmaxf(ss, 0.0f)), 1e-8f);
    }
    __syncthreads();

    for (int ch = 0; ch < 4; ++ch) {
        float mu = muL[node], inv = invL[node];
#pragma unroll 4
        for (int j = 0; j < 32; ++j) {
            int cl = cq * 32 + j;
            float x = src[(ch * 128 + cl) * 64 + node];
            tile[cl][node] = (x - mu) * inv;
        }
        __syncthreads();
#pragma unroll
        for (int r = 0; r < 4; ++r) {
            int lin = r * 256 + threadIdx.x;
            int nd  = lin >> 4;
            int c8  = lin & 15;
            half8 v;
#pragma unroll
            for (int i = 0; i < 8; ++i) v[i] = (_Float16)tile[c8 * 8 + i][nd];
            *(half8*)(dst + (size_t)nd * 512 + ch * 128 + c8 * 8) = v;
        }
        __syncthreads();
    }
}

// --------- K2a: a-marginals. Weights via broadcast b128 reads ---------------
__global__ void __launch_bounds__(256)
amarg_kernel(const float* __restrict__ query, const float* __restrict__ BpT,
             float* __restrict__ a_out) {
    __shared__ __align__(16) float BpL[512 * 32];   // [c][w] 64 KB
    int q    = blockIdx.x;
    int lane = threadIdx.x & 63;   // node
    int wq   = threadIdx.x >> 6;   // w = wq*8 .. +7
    for (int t = threadIdx.x; t < 4096; t += 256)
        ((float4*)BpL)[t] = ((const float4*)BpT)[t];
    __syncthreads();
    float acc[8] = {0, 0, 0, 0, 0, 0, 0, 0};
    for (int c = 0; c < 512; ++c) {
        float x = query[((size_t)q * 512 + c) * 64 + lane];
        float4 b0 = *(const float4*)(BpL + c * 32 + wq * 8);      // broadcast
        float4 b1 = *(const float4*)(BpL + c * 32 + wq * 8 + 4);  // broadcast
        acc[0] = fmaf(x, b0.x, acc[0]); acc[1] = fmaf(x, b0.y, acc[1]);
        acc[2] = fmaf(x, b0.z, acc[2]); acc[3] = fmaf(x, b0.w, acc[3]);
        acc[4] = fmaf(x, b1.x, acc[4]); acc[5] = fmaf(x, b1.y, acc[5]);
        acc[6] = fmaf(x, b1.z, acc[6]); acc[7] = fmaf(x, b1.w, acc[7]);
    }
#pragma unroll
    for (int k = 0; k < 8; ++k) {
        float v = fmaxf(acc[k], 0.0f) + 0.001f;
        v += 1e-5f;
        float s = v;
        s += __shfl_xor(s, 1);  s += __shfl_xor(s, 2);  s += __shfl_xor(s, 4);
        s += __shfl_xor(s, 8);  s += __shfl_xor(s, 16); s += __shfl_xor(s, 32);
        int w = wq * 8 + k;
        a_out[((size_t)q * 32 + w) * 64 + lane] = v * (64.0f / s);
    }
}

// --------- K2b: b-marginals. Same trick, q-group of 32 ----------------------
__global__ void __launch_bounds__(256)
bmarg_kernel(const float* __restrict__ support, const float* __restrict__ QpT,
             float* __restrict__ b_out) {
    __shared__ __align__(16) float QpL[512 * 32];   // [c][qlocal] 64 KB
    int w    = blockIdx.x >> 3;
    int qg   = blockIdx.x & 7;     // q base qg*32
    int lane = threadIdx.x & 63;   // node
    int qq   = threadIdx.x >> 6;   // qlocal = qq*8 .. +7
    for (int t = threadIdx.x; t < 4096; t += 256) {
        int c = t >> 3, k = t & 7;
        ((float4*)QpL)[t] = ((const float4*)(QpT + (size_t)c * 256 + qg * 32))[k];
    }
    __syncthreads();
    float acc[8] = {0, 0, 0, 0, 0, 0, 0, 0};
    for (int c = 0; c < 512; ++c) {
        float x = support[((size_t)w * 512 + c) * 64 + lane];
        float4 b0 = *(const float4*)(QpL + c * 32 + qq * 8);
        float4 b1 = *(const float4*)(QpL + c * 32 + qq * 8 + 4);
        acc[0] = fmaf(x, b0.x, acc[0]); acc[1] = fmaf(x, b0.y, acc[1]);
        acc[2] = fmaf(x, b0.z, acc[2]); acc[3] = fmaf(x, b0.w, acc[3]);
        acc[4] = fmaf(x, b1.x, acc[4]); acc[5] = fmaf(x, b1.y, acc[5]);
        acc[6] = fmaf(x, b1.z, acc[6]); acc[7] = fmaf(x, b1.w, acc[7]);
    }
#pragma unroll
    for (int k = 0; k < 8; ++k) {
        float v = fmaxf(acc[k], 0.0f) + 0.001f;
        v += 1e-5f;
        float s = v;
        s += __shfl_xor(s, 1);  s += __shfl_xor(s, 2);  s += __shfl_xor(s, 4);
        s += __shfl_xor(s, 8);  s += __shfl_xor(s, 16); s += __shfl_xor(s, 32);
        int q = qg * 32 + qq * 8 + k;
        b_out[((size_t)w * 256 + q) * 64 + lane] = v * (64.0f / s);
    }
}

// --------- K3: MFMA sim + permuted transpose + fp16-M Sinkhorn + logits -----
// Wave per (q,w). lane=(ig,jg). Permuted layout Mh[t][s]=M'[ig*8+(jg^t)][jg*8+(ig^s)]
// with M' = 2^((sim - smax)*K_SIM2M) (per-tile rescale; flow is scale-invariant,
// sim recovered as smax + log2(M')*K_M2SIM).
__global__ void __launch_bounds__(256, 4)
emd_kernel(const _Float16* __restrict__ Uht, const _Float16* __restrict__ Vht,
           const float* __restrict__ a_arr, const float* __restrict__ b_arr,
           float* __restrict__ out) {
    __shared__ __align__(16) float T[2][64 * 64];   // 32 KB

    int bid  = blockIdx.x;          // 2048
    int w    = bid & 31;
    int qg   = bid >> 5;
    int wave = threadIdx.x >> 6;
    int lane = threadIdx.x & 63;
    int q    = qg * 4 + wave;
    int lo16 = lane & 15;
    int hi4  = lane >> 4;
    int ig   = lane >> 3;
    int jg   = lane & 7;

    // ---- phase 1: sim tile via fp16 MFMA ----
    floatx4 acc[4][4];
#pragma unroll
    for (int tm = 0; tm < 4; ++tm)
#pragma unroll
        for (int tn = 0; tn < 4; ++tn)
            acc[tm][tn] = (floatx4){0.f, 0.f, 0.f, 0.f};

    const _Float16* Abase = Uht + (size_t)q * 32768;
    const _Float16* Bbase = Vht + (size_t)w * 32768;
#pragma unroll 1
    for (int kk = 0; kk < 16; ++kk) {
        int kc = kk * 32 + hi4 * 8;
        half8 bf[4];
#pragma unroll
        for (int t = 0; t < 4; ++t)
            bf[t] = *(const half8*)(Bbase + (size_t)(t * 16 + lo16) * 512 + kc);
#pragma unroll
        for (int tm = 0; tm < 4; ++tm) {
            half8 af = *(const half8*)(Abase + (size_t)(tm * 16 + lo16) * 512 + kc);
#pragma unroll
            for (int tn = 0; tn < 4; ++tn)
                acc[tm][tn] = __builtin_amdgcn_mfma_f32_16x16x32_f16(
                    af, bf[tn], acc[tm][tn], 0, 0, 0);
        }
    }

    // ---- tile max (wave-uniform) for fp16 rescale ----
    float lmax = -2.0f;
#pragma unroll
    for (int tm = 0; tm < 4; ++tm)
#pragma unroll
        for (int tn = 0; tn < 4; ++tn)
#pragma unroll
            for (int r = 0; r < 4; ++r) lmax = fmaxf(lmax, acc[tm][tn][r]);
    lmax = fmaxf(lmax, __shfl_xor(lmax, 1));
    lmax = fmaxf(lmax, __shfl_xor(lmax, 2));
    lmax = fmaxf(lmax, __shfl_xor(lmax, 4));
    lmax = fmaxf(lmax, __shfl_xor(lmax, 8));
    lmax = fmaxf(lmax, __shfl_xor(lmax, 16));
    lmax = fmaxf(lmax, __shfl_xor(lmax, 32));
    float s0 = lmax;

    // ---- phase 2: exp + LDS roundtrip into permuted layout, fp16 on read ---
    half8 Mh[8];   // Mh[t][s] : 32 VGPRs total
#pragma unroll 1
    for (int round = 0; round < 2; ++round) {
        if ((wave >> 1) == round) {
            float* buf = T[wave & 1];
#pragma unroll
            for (int tm = 0; tm < 4; ++tm)
#pragma unroll
                for (int tn = 0; tn < 4; ++tn)
#pragma unroll
                    for (int r = 0; r < 4; ++r) {
                        int row = tm * 16 + hi4 * 4 + r;
                        int col = tn * 16 + lo16;
                        int sp  = (col & 7) ^ (row >> 3);
                        buf[row * 64 + (col & ~7) + sp] =
                            fexp2((acc[tm][tn][r] - s0) * K_SIM2M);
                    }
        }
        __syncthreads();
        if ((wave >> 1) == round) {
            const float* buf = T[wave & 1];
#pragma unroll
            for (int t = 0; t < 8; ++t) {
                const float* p = buf + (ig * 8 + (jg ^ t)) * 64 + jg * 8;
                float4 m0 = *(const float4*)p;
                float4 m1 = *(const float4*)(p + 4);
                half8 h;
                h[0] = (_Float16)m0.x; h[1] = (_Float16)m0.y;
                h[2] = (_Float16)m0.z; h[3] = (_Float16)m0.w;
                h[4] = (_Float16)m1.x; h[5] = (_Float16)m1.y;
                h[6] = (_Float16)m1.z; h[7] = (_Float16)m1.w;
                Mh[t] = h;
            }
        }
        __syncthreads();
    }

    float a_own = a_arr[((size_t)q * 32 + w) * 64 + ig * 8 + jg];
    float b_own = b_arr[((size_t)w * 256 + q) * 64 + jg * 8 + ig];

    // ---- phase 3: Sinkhorn, reduce-scatter + all-gather, tol early exit ----
    float wvp[8];
#pragma unroll
    for (int s = 0; s < 8; ++s) wvp[s] = 1.0f;
    float q8[8];
    float z_prev = -1.f, w_prev = -1.f;

#pragma unroll 1
    for (int it = 0; it < 100; ++it) {
        float p[8];
#pragma unroll
        for (int t = 0; t < 8; ++t) {
            float s = (float)Mh[t][0] * wvp[0];
#pragma unroll
            for (int c = 1; c < 8; ++c) s = fmaf((float)Mh[t][c], wvp[c], s);
            p[t] = s;
        }
        p[0] += __shfl_xor(p[4], 4); p[1] += __shfl_xor(p[5], 4);
        p[2] += __shfl_xor(p[6], 4); p[3] += __shfl_xor(p[7], 4);
        p[0] += __shfl_xor(p[2], 2); p[1] += __shfl_xor(p[3], 2);
        p[0] += __shfl_xor(p[1], 1);
        float z_own = a_own * fast_rcp(p[0]);
        q8[0] = z_own;
        q8[1] = __shfl_xor(q8[0], 1);
        q8[2] = __shfl_xor(q8[0], 2); q8[3] = __shfl_xor(q8[1], 2);
        q8[4] = __shfl_xor(q8[0], 4); q8[5] = __shfl_xor(q8[1], 4);
        q8[6] = __shfl_xor(q8[2], 4); q8[7] = __shfl_xor(q8[3], 4);
        float cp[8];
#pragma unroll
        for (int s = 0; s < 8; ++s) {
            float v = (float)Mh[0][s] * q8[0];
#pragma unroll
            for (int t = 1; t < 8; ++t) v = fmaf((float)Mh[t][s], q8[t], v);
            cp[s] = v;
        }
        cp[0] += __shfl_xor(cp[4], 32); cp[1] += __shfl_xor(cp[5], 32);
        cp[2] += __shfl_xor(cp[6], 32); cp[3] += __shfl_xor(cp[7], 32);
        cp[0] += __shfl_xor(cp[2], 16); cp[1] += __shfl_xor(cp[3], 16);
        cp[0] += __shfl_xor(cp[1], 8);
        float w_own = b_own * fast_rcp(cp[0]);
        wvp[0] = w_own;
        wvp[1] = __shfl_xor(wvp[0], 8);
        wvp[2] = __shfl_xor(wvp[0], 16); wvp[3] = __shfl_xor(wvp[1], 16);
        wvp[4] = __shfl_xor(wvp[0], 32); wvp[5] = __shfl_xor(wvp[1], 32);
        wvp[6] = __shfl_xor(wvp[2], 32); wvp[7] = __shfl_xor(wvp[3], 32);
        // tolerance exit: both potentials stable to 1e-5 rel across the wave
        bool same = (fabsf(z_own - z_prev) <= 1e-5f * z_own) &&
                    (fabsf(w_own - w_prev) <= 1e-5f * w_own);
        z_prev = z_own; w_prev = w_own;
        if (__all(same)) break;
    }

    // ---- phase 4: logits; sim = s0 + log2(M')*eps*ln2 ----
    float s = 0.f;
#pragma unroll
    for (int t = 0; t < 8; ++t)
#pragma unroll
        for (int c = 0; c < 8; ++c) {
            float m    = fmaxf((float)Mh[t][c], 1e-30f);  // guard log(0)
            float sim  = fmaf(flog2(m), K_M2SIM, s0);
            float flow = q8[t] * m * wvp[c];
            s = fmaf(sim, flow, s);
        }
    s += __shfl_xor(s, 1);  s += __shfl_xor(s, 2);  s += __shfl_xor(s, 4);
    s += __shfl_xor(s, 8);  s += __shfl_xor(s, 16); s += __shfl_xor(s, 32);
    if (lane == 0) out[q * 32 + w] = s * 0.1953125f;   // 12.5/64
}

// ---------------------------------------------------------------------------
extern "C" void kernel_launch(void* const* d_in, const int* in_sizes, int n_in,
                              void* d_out, int out_size, void* d_ws, size_t ws_size,
                              hipStream_t stream) {
    (void)in_sizes; (void)n_in; (void)out_size; (void)ws_size;
    const float* support = (const float*)d_in[0];   // 32*512*64
    const float* query   = (const float*)d_in[1];   // 256*512*64

    _Float16* Uht = (_Float16*)d_ws;                // 16 MB
    _Float16* Vht = Uht + 8388608;                  //  2 MB
    float* BpT = (float*)(Vht + 1048576);           // [512][32]
    float* QpT = BpT + 16384;                       // [512][256]
    float* aA  = QpT + 131072;
    float* bA  = aA + 524288;

    norm_kernel <<<288, 256, 0, stream>>>(support, query, Vht, Uht, BpT, QpT);
    amarg_kernel<<<256, 256, 0, stream>>>(query, BpT, aA);
    bmarg_kernel<<<256, 256, 0, stream>>>(support, QpT, bA);
    emd_kernel  <<<2048, 256, 0, stream>>>(Uht, Vht, aA, bA, (float*)d_out);
}